// Round 1
// baseline (726.892 us; speedup 1.0000x reference)
//
#include <hip/hip_runtime.h>
#include <hip/hip_fp16.h>

typedef _Float16 f16;
typedef __attribute__((ext_vector_type(8))) _Float16 f16x8;
typedef __attribute__((ext_vector_type(4))) float f32x4;

#define NPTS 8192
#define DIM  1024
#define L2E  1.44269504088896f
#define SHIFT 40.0f   // ~E[colmax]; centers fp16-stored scores near 0 (cancels in softmax)

// ---------- fp32 -> fp16 convert (vectorized, n multiple of 8) ----------
__global__ void cvt_f32_f16(const float* __restrict__ src, f16* __restrict__ dst, int n) {
  int i = (blockIdx.x * 256 + threadIdx.x) * 8;
  if (i >= n) return;
  const float4* s = (const float4*)(src + i);
  float4 a = s[0], b = s[1];
  f16x8 o;
  o[0] = (f16)a.x; o[1] = (f16)a.y; o[2] = (f16)a.z; o[3] = (f16)a.w;
  o[4] = (f16)b.x; o[5] = (f16)b.y; o[6] = (f16)b.z; o[7] = (f16)b.w;
  *(f16x8*)(dst + i) = o;
}

// ---------- C = A * B^T (+bias) f16 MFMA GEMM, 128x128 tile, BK=32 ----------
// A: [M x K] row-major f16, lda
// B: [N x K] row-major f16 (i.e. B^T form), ldb
// EPI 0: f16 C[i,n] = acc + bias[n] - shift          (ldc row stride)
// EPI 1: f16 C[n*ldc + i] = acc + bias[n]            (transposed write)
// EPI 2: f32 C[i,n] = acc + Res[i*ldr + n]           (residual, fp32 out)
template<int EPI>
__global__ __launch_bounds__(256, 2)
void gemm_bt(const f16* __restrict__ A, int lda,
             const f16* __restrict__ B, int ldb,
             int M, int N, int K,
             const float* __restrict__ bias,
             void* __restrict__ Cout, int ldc,
             const float* __restrict__ Res, int ldr,
             float shift) {
  const int SROW = 40;                 // 32 + 8 pad: b128 frag reads ~2-way (free)
  __shared__ f16 sA[128 * SROW];
  __shared__ f16 sB[128 * SROW];
  const int t = threadIdx.x;
  const int w = t >> 6, l = t & 63;
  const int wm = (w >> 1) * 64, wn = (w & 1) * 64;   // 2x2 waves, 64x64 each
  const long bi = (long)blockIdx.y * 128, bj = (long)blockIdx.x * 128;
  const int lr = l & 15, lk = (l >> 4) * 8;          // frag row / contiguous-k base

  // staging map: thread -> (row t>>2, 8-elem chunk t&3); two passes cover 128 rows
  const int sr = t >> 2;
  const int sc = (t & 3) * 8;
  const f16* gA = A + (bi + sr) * (long)lda + sc;
  const f16* gB = B + (bj + sr) * (long)ldb + sc;

  f32x4 acc[4][4] = {};

  uint4 ra0 = *(const uint4*)gA;
  uint4 ra1 = *(const uint4*)(gA + 64l * lda);
  uint4 rb0 = *(const uint4*)gB;
  uint4 rb1 = *(const uint4*)(gB + 64l * ldb);

  for (int k0 = 0; k0 < K; k0 += 32) {
    __syncthreads();                       // prior iter's frag reads done
    *(uint4*)(sA + sr * SROW + sc)        = ra0;
    *(uint4*)(sA + (sr + 64) * SROW + sc) = ra1;
    *(uint4*)(sB + sr * SROW + sc)        = rb0;
    *(uint4*)(sB + (sr + 64) * SROW + sc) = rb1;
    __syncthreads();
    if (k0 + 32 < K) {                     // prefetch next tile over the MFMAs
      gA += 32; gB += 32;
      ra0 = *(const uint4*)gA;
      ra1 = *(const uint4*)(gA + 64l * lda);
      rb0 = *(const uint4*)gB;
      rb1 = *(const uint4*)(gB + 64l * ldb);
    }
    f16x8 af[4], bf[4];
#pragma unroll
    for (int mt = 0; mt < 4; mt++)
      af[mt] = *(const f16x8*)(sA + (wm + mt * 16 + lr) * SROW + lk);
#pragma unroll
    for (int nt = 0; nt < 4; nt++)
      bf[nt] = *(const f16x8*)(sB + (wn + nt * 16 + lr) * SROW + lk);
#pragma unroll
    for (int mt = 0; mt < 4; mt++)
#pragma unroll
      for (int nt = 0; nt < 4; nt++)
        acc[mt][nt] = __builtin_amdgcn_mfma_f32_16x16x32_f16(af[mt], bf[nt], acc[mt][nt], 0, 0, 0);
  }

  // C/D layout (m89-verified): col = l&15, row = (l>>4)*4 + reg
  const int rbase = (l >> 4) * 4;
#pragma unroll
  for (int mt = 0; mt < 4; mt++) {
#pragma unroll
    for (int nt = 0; nt < 4; nt++) {
      const long col  = bj + wn + nt * 16 + lr;
      const long row0 = bi + wm + mt * 16 + rbase;
      if (EPI == 0) {
        float bb = (bias ? bias[col] : 0.f) - shift;
        f16* C = (f16*)Cout;
#pragma unroll
        for (int g = 0; g < 4; g++)
          C[(row0 + g) * ldc + col] = (f16)(acc[mt][nt][g] + bb);
      } else if (EPI == 1) {
        float bb = bias ? bias[col] : 0.f;
        union { unsigned long long u; f16 h[4]; } pk;
#pragma unroll
        for (int g = 0; g < 4; g++) pk.h[g] = (f16)(acc[mt][nt][g] + bb);
        *(unsigned long long*)((f16*)Cout + col * (long)ldc + row0) = pk.u;  // 8B store
      } else {
        float* C = (float*)Cout;
#pragma unroll
        for (int g = 0; g < 4; g++)
          C[(row0 + g) * ldc + col] = acc[mt][nt][g] + Res[(row0 + g) * (long)ldr + col];
      }
    }
  }
}

// ---------- per-column partial sum of exp(stored score) ----------
// grid (4 col-groups, 64 row-groups), block 256; thread owns 8 consecutive cols
__global__ void col_partial(const f16* __restrict__ S, float* __restrict__ psum) {
  const int j0 = blockIdx.x * 2048 + threadIdx.x * 8;
  const long r0 = (long)blockIdx.y * 128;
  float s[8];
#pragma unroll
  for (int e = 0; e < 8; e++) s[e] = 0.f;
  for (int r = 0; r < 128; r++) {
    f16x8 v = *(const f16x8*)(S + (r0 + r) * NPTS + j0);
#pragma unroll
    for (int e = 0; e < 8; e++) s[e] += exp2f((float)v[e] * L2E);
  }
#pragma unroll
  for (int e = 0; e < 8; e++) psum[blockIdx.y * NPTS + j0 + e] = s[e];
}

__global__ void col_combine(const float* __restrict__ psum, float* __restrict__ inv_cs) {
  const int j = blockIdx.x * 256 + threadIdx.x;
  float s = 0.f;
  for (int b = 0; b < 64; b++) s += psum[b * NPTS + j];
  inv_cs[j] = 1.0f / s;
}

// ---------- P[i,j] = exp(S[i,j]) * inv_cs[j], in place ----------
__global__ void p_exp(f16* __restrict__ S, const float* __restrict__ inv_cs) {
  const int j0 = blockIdx.x * 2048 + threadIdx.x * 8;
  const long r0 = (long)blockIdx.y * 128;
  float ic[8];
#pragma unroll
  for (int e = 0; e < 8; e++) ic[e] = inv_cs[j0 + e];
  for (int r = 0; r < 128; r++) {
    f16* ptr = S + (r0 + r) * NPTS + j0;
    f16x8 v = *(const f16x8*)ptr;
    f16x8 o;
#pragma unroll
    for (int e = 0; e < 8; e++) o[e] = (f16)(exp2f((float)v[e] * L2E) * ic[e]);
    *(f16x8*)ptr = o;
  }
}

extern "C" void kernel_launch(void* const* d_in, const int* in_sizes, int n_in,
                              void* d_out, int out_size, void* d_ws, size_t ws_size,
                              hipStream_t stream) {
  const float* p  = (const float*)d_in[0];
  const float* r  = (const float*)d_in[1];
  const float* Wh = (const float*)d_in[2];
  const float* bh = (const float*)d_in[3];
  const float* Wl = (const float*)d_in[4];
  const float* bl = (const float*)d_in[5];
  const float* Wg = (const float*)d_in[6];
  const float* bg = (const float*)d_in[7];
  float* out = (float*)d_out;

  char* ws = (char*)d_ws;
  f16* q_h  = (f16*)(ws + (0ull  << 20));   // 16 MB [N,D]
  f16* k_h  = (f16*)(ws + (16ull << 20));   // 16 MB [N,D]
  f16* vt_h = (f16*)(ws + (32ull << 20));   // 16 MB [D,N] (transposed v)
  f16* p_h  = (f16*)(ws + (48ull << 20));   // 16 MB
  f16* r_h  = (f16*)(ws + (64ull << 20));   // 16 MB
  f16* wh_h = (f16*)(ws + (80ull << 20));   // 2 MB
  f16* wl_h = (f16*)(ws + (82ull << 20));
  f16* wg_h = (f16*)(ws + (84ull << 20));
  f16* S    = (f16*)(ws + (96ull << 20));   // 128 MB [N,N]
  float* psum   = (float*)(ws + (224ull << 20));  // 2 MB [64][N]
  float* inv_cs = (float*)(ws + (227ull << 20));  // 32 KB

  const int nP = NPTS * DIM, nW = DIM * DIM;
  cvt_f32_f16<<<nP / 2048, 256, 0, stream>>>(p,  p_h,  nP);
  cvt_f32_f16<<<nP / 2048, 256, 0, stream>>>(r,  r_h,  nP);
  cvt_f32_f16<<<nW / 2048, 256, 0, stream>>>(Wh, wh_h, nW);
  cvt_f32_f16<<<nW / 2048, 256, 0, stream>>>(Wl, wl_h, nW);
  cvt_f32_f16<<<nW / 2048, 256, 0, stream>>>(Wg, wg_h, nW);

  dim3 blk(256);
  // q = p@Wh^T + bh ; k = r@Wl^T + bl ; vt = (p@Wg^T + bg)^T
  gemm_bt<0><<<dim3(DIM / 128, NPTS / 128), blk, 0, stream>>>(
      p_h, DIM, wh_h, DIM, NPTS, DIM, DIM, bh, q_h, DIM, nullptr, 0, 0.f);
  gemm_bt<0><<<dim3(DIM / 128, NPTS / 128), blk, 0, stream>>>(
      r_h, DIM, wl_h, DIM, NPTS, DIM, DIM, bl, k_h, DIM, nullptr, 0, 0.f);
  gemm_bt<1><<<dim3(DIM / 128, NPTS / 128), blk, 0, stream>>>(
      p_h, DIM, wg_h, DIM, NPTS, DIM, DIM, bg, vt_h, NPTS, nullptr, 0, 0.f);
  // S = q k^T - SHIFT   (fp16 store)
  gemm_bt<0><<<dim3(NPTS / 128, NPTS / 128), blk, 0, stream>>>(
      q_h, DIM, k_h, DIM, NPTS, NPTS, DIM, nullptr, S, NPTS, nullptr, 0, SHIFT);
  // column softmax denominators (no max needed: fp32 exp range suffices)
  col_partial<<<dim3(4, 64), blk, 0, stream>>>(S, psum);
  col_combine<<<NPTS / 256, blk, 0, stream>>>(psum, inv_cs);
  p_exp<<<dim3(4, 64), blk, 0, stream>>>(S, inv_cs);
  // out = P @ v + p   (P as A, vt as B^T-form, fp32 residual epilogue)
  gemm_bt<2><<<dim3(DIM / 128, NPTS / 128), blk, 0, stream>>>(
      S, NPTS, vt_h, NPTS, NPTS, DIM, NPTS, nullptr, out, DIM, p, DIM, 0.f);
}

// Round 2
// 707.172 us; speedup vs baseline: 1.0279x; 1.0279x over previous
//
#include <hip/hip_runtime.h>
#include <hip/hip_fp16.h>

typedef _Float16 f16;
typedef __attribute__((ext_vector_type(8))) _Float16 f16x8;
typedef __attribute__((ext_vector_type(4))) float f32x4;

#define NPTS 8192
#define DIM  1024
#define L2E  1.44269504088896f
#define SHIFT 40.0f   // ~E[colmax]; centers fp16-stored scores near 0 (cancels in softmax)

// ---------- fp32 -> fp16 convert (vectorized, n multiple of 8) ----------
__global__ void cvt_f32_f16(const float* __restrict__ src, f16* __restrict__ dst, int n) {
  int i = (blockIdx.x * 256 + threadIdx.x) * 8;
  if (i >= n) return;
  const float4* s = (const float4*)(src + i);
  float4 a = s[0], b = s[1];
  f16x8 o;
  o[0] = (f16)a.x; o[1] = (f16)a.y; o[2] = (f16)a.z; o[3] = (f16)a.w;
  o[4] = (f16)b.x; o[5] = (f16)b.y; o[6] = (f16)b.z; o[7] = (f16)b.w;
  *(f16x8*)(dst + i) = o;
}

__global__ void zero_f32(float* __restrict__ p, int n) {
  int i = blockIdx.x * 256 + threadIdx.x;
  if (i < n) p[i] = 0.f;
}

__global__ void inv_f32(float* __restrict__ p, int n) {
  int i = blockIdx.x * 256 + threadIdx.x;
  if (i < n) p[i] = 1.0f / p[i];
}

// exp2(s*log2e) * inv_cs, elementwise on an 8-wide f16 chunk (PV A-staging)
__device__ __forceinline__ f16x8 expscale(f16x8 s, float4 i0, float4 i1) {
  f16x8 o;
  o[0] = (f16)(exp2f((float)s[0] * L2E) * i0.x);
  o[1] = (f16)(exp2f((float)s[1] * L2E) * i0.y);
  o[2] = (f16)(exp2f((float)s[2] * L2E) * i0.z);
  o[3] = (f16)(exp2f((float)s[3] * L2E) * i0.w);
  o[4] = (f16)(exp2f((float)s[4] * L2E) * i1.x);
  o[5] = (f16)(exp2f((float)s[5] * L2E) * i1.y);
  o[6] = (f16)(exp2f((float)s[6] * L2E) * i1.z);
  o[7] = (f16)(exp2f((float)s[7] * L2E) * i1.w);
  return o;
}

// ---------- C = A * B^T (+bias) f16 MFMA GEMM, 128x128 tile, BK=32 ----------
// A: [M x K] row-major f16, lda ; B: [N x K] row-major f16, ldb
// EPI 0: f16 C[i,n] = acc + bias[n] - shift
// EPI 1: f16 C[n*ldc + i] = acc + bias[n]              (transposed write, for v^T)
// EPI 3: PV — A-staging applies exp2(s)*inv_cs[k] (xtra=inv_cs);
//        f32 C[i,n] = acc + Res[i*ldr + n]
// EPI 4: QK^T — f16 C[i,n] = acc - shift; atomicAdd per-column sum of
//        exp(rounded score) into xtra (colsum)
// SWZ 1: 1D grid of (M/128)*(N/128) with row = b&63, col = b>>6 — puts all
//        N/128=8 col-tiles of one row-block on the same XCD (b%8 round-robin)
//        so the A row-panel is fetched from fabric once and L2-hit 7 times.
//        (Requires M=8192, N=1024.)
template<int EPI, int SWZ>
__global__ __launch_bounds__(256, 2)
void gemm_bt(const f16* __restrict__ A, int lda,
             const f16* __restrict__ B, int ldb,
             int M, int N, int K,
             const float* __restrict__ bias,
             void* __restrict__ Cout, int ldc,
             const float* __restrict__ Res, int ldr,
             float shift, float* __restrict__ xtra) {
  const int SROW = 40;                 // 32 + 8 pad: b128 frag reads ~2-way (free)
  __shared__ f16 sA[128 * SROW];
  __shared__ f16 sB[128 * SROW];
  const int t = threadIdx.x;
  const int w = t >> 6, l = t & 63;
  const int wm = (w >> 1) * 64, wn = (w & 1) * 64;   // 2x2 waves, 64x64 each
  long bi, bj;
  if (SWZ) {
    const int b = blockIdx.x;
    bi = (long)(b & 63) * 128;         // M/128 == 64
    bj = (long)(b >> 6) * 128;
  } else {
    bi = (long)blockIdx.y * 128;
    bj = (long)blockIdx.x * 128;
  }
  const int lr = l & 15, lk = (l >> 4) * 8;          // frag row / contiguous-k base

  // staging map: thread -> (row t>>2, 8-elem chunk t&3); two passes cover 128 rows
  const int sr = t >> 2;
  const int sc = (t & 3) * 8;
  const f16* gA = A + (bi + sr) * (long)lda + sc;
  const f16* gB = B + (bj + sr) * (long)ldb + sc;

  f32x4 acc[4][4] = {};

  uint4 ra0 = *(const uint4*)gA;
  uint4 ra1 = *(const uint4*)(gA + 64l * lda);
  uint4 rb0 = *(const uint4*)gB;
  uint4 rb1 = *(const uint4*)(gB + 64l * ldb);
  float4 ic0 = {}, ic1 = {};
  if (EPI == 3) {
    ic0 = *(const float4*)(xtra + sc);
    ic1 = *(const float4*)(xtra + sc + 4);
  }

  for (int k0 = 0; k0 < K; k0 += 32) {
    __syncthreads();                       // prior iter's frag reads done
    if (EPI == 3) {                        // P = exp(S)*inv_cs — never overflows f16
      *(f16x8*)(sA + sr * SROW + sc)        = expscale(*(f16x8*)&ra0, ic0, ic1);
      *(f16x8*)(sA + (sr + 64) * SROW + sc) = expscale(*(f16x8*)&ra1, ic0, ic1);
    } else {
      *(uint4*)(sA + sr * SROW + sc)        = ra0;
      *(uint4*)(sA + (sr + 64) * SROW + sc) = ra1;
    }
    *(uint4*)(sB + sr * SROW + sc)        = rb0;
    *(uint4*)(sB + (sr + 64) * SROW + sc) = rb1;
    __syncthreads();
    if (k0 + 32 < K) {                     // prefetch next tile over the MFMAs
      gA += 32; gB += 32;
      ra0 = *(const uint4*)gA;
      ra1 = *(const uint4*)(gA + 64l * lda);
      rb0 = *(const uint4*)gB;
      rb1 = *(const uint4*)(gB + 64l * ldb);
      if (EPI == 3) {
        ic0 = *(const float4*)(xtra + k0 + 32 + sc);
        ic1 = *(const float4*)(xtra + k0 + 32 + sc + 4);
      }
    }
    f16x8 af[4], bf[4];
#pragma unroll
    for (int mt = 0; mt < 4; mt++)
      af[mt] = *(const f16x8*)(sA + (wm + mt * 16 + lr) * SROW + lk);
#pragma unroll
    for (int nt = 0; nt < 4; nt++)
      bf[nt] = *(const f16x8*)(sB + (wn + nt * 16 + lr) * SROW + lk);
#pragma unroll
    for (int mt = 0; mt < 4; mt++)
#pragma unroll
      for (int nt = 0; nt < 4; nt++)
        acc[mt][nt] = __builtin_amdgcn_mfma_f32_16x16x32_f16(af[mt], bf[nt], acc[mt][nt], 0, 0, 0);
  }

  // C/D layout (m89-verified): col = l&15, row = (l>>4)*4 + reg
  const int rbase = (l >> 4) * 4;
#pragma unroll
  for (int nt = 0; nt < 4; nt++) {
    const long col = bj + wn + nt * 16 + lr;
    float csum = 0.f;
#pragma unroll
    for (int mt = 0; mt < 4; mt++) {
      const long row0 = bi + wm + mt * 16 + rbase;
      if (EPI == 0) {
        float bb = (bias ? bias[col] : 0.f) - shift;
        f16* C = (f16*)Cout;
#pragma unroll
        for (int g = 0; g < 4; g++)
          C[(row0 + g) * ldc + col] = (f16)(acc[mt][nt][g] + bb);
      } else if (EPI == 1) {
        float bb = bias ? bias[col] : 0.f;
        union { unsigned long long u; f16 h[4]; } pk;
#pragma unroll
        for (int g = 0; g < 4; g++) pk.h[g] = (f16)(acc[mt][nt][g] + bb);
        *(unsigned long long*)((f16*)Cout + col * (long)ldc + row0) = pk.u;  // 8B store
      } else if (EPI == 3) {
        float* C = (float*)Cout;
#pragma unroll
        for (int g = 0; g < 4; g++)
          C[(row0 + g) * ldc + col] = acc[mt][nt][g] + Res[(row0 + g) * (long)ldr + col];
      } else { // EPI 4: shifted f16 score + column exp-sum from the ROUNDED value
        f16* C = (f16*)Cout;
#pragma unroll
        for (int g = 0; g < 4; g++) {
          f16 sh = (f16)(acc[mt][nt][g] - shift);
          C[(row0 + g) * ldc + col] = sh;
          csum += exp2f((float)sh * L2E);   // fp32: max e^24, no overflow
        }
      }
    }
    if (EPI == 4) {
      csum += __shfl_xor(csum, 16);
      csum += __shfl_xor(csum, 32);
      if (l < 16) atomicAdd(xtra + col, csum);
    }
  }
}

extern "C" void kernel_launch(void* const* d_in, const int* in_sizes, int n_in,
                              void* d_out, int out_size, void* d_ws, size_t ws_size,
                              hipStream_t stream) {
  const float* p  = (const float*)d_in[0];
  const float* r  = (const float*)d_in[1];
  const float* Wh = (const float*)d_in[2];
  const float* bh = (const float*)d_in[3];
  const float* Wl = (const float*)d_in[4];
  const float* bl = (const float*)d_in[5];
  const float* Wg = (const float*)d_in[6];
  const float* bg = (const float*)d_in[7];
  float* out = (float*)d_out;

  char* ws = (char*)d_ws;
  f16* q_h  = (f16*)(ws + (0ull  << 20));   // 16 MB [N,D]
  f16* k_h  = (f16*)(ws + (16ull << 20));   // 16 MB [N,D]
  f16* vt_h = (f16*)(ws + (32ull << 20));   // 16 MB [D,N] (transposed v)
  f16* p_h  = (f16*)(ws + (48ull << 20));   // 16 MB
  f16* r_h  = (f16*)(ws + (64ull << 20));   // 16 MB
  f16* wh_h = (f16*)(ws + (80ull << 20));   // 2 MB
  f16* wl_h = (f16*)(ws + (82ull << 20));
  f16* wg_h = (f16*)(ws + (84ull << 20));
  f16* S    = (f16*)(ws + (96ull << 20));   // 128 MB [N,N] raw shifted scores
  float* colsum = (float*)(ws + (224ull << 20));  // 32 KB; becomes inv_cs in place

  const int nP = NPTS * DIM, nW = DIM * DIM;
  cvt_f32_f16<<<nP / 2048, 256, 0, stream>>>(p,  p_h,  nP);
  cvt_f32_f16<<<nP / 2048, 256, 0, stream>>>(r,  r_h,  nP);
  cvt_f32_f16<<<nW / 2048, 256, 0, stream>>>(Wh, wh_h, nW);
  cvt_f32_f16<<<nW / 2048, 256, 0, stream>>>(Wl, wl_h, nW);
  cvt_f32_f16<<<nW / 2048, 256, 0, stream>>>(Wg, wg_h, nW);
  zero_f32<<<NPTS / 256, 256, 0, stream>>>(colsum, NPTS);

  dim3 blk(256);
  // Projections: swizzled 1D grid (512 blocks, 2/CU, row-panel L2 reuse)
  gemm_bt<0, 1><<<512, blk, 0, stream>>>(
      p_h, DIM, wh_h, DIM, NPTS, DIM, DIM, bh, q_h, DIM, nullptr, 0, 0.f, nullptr);
  gemm_bt<0, 1><<<512, blk, 0, stream>>>(
      r_h, DIM, wl_h, DIM, NPTS, DIM, DIM, bl, k_h, DIM, nullptr, 0, 0.f, nullptr);
  gemm_bt<1, 1><<<512, blk, 0, stream>>>(
      p_h, DIM, wg_h, DIM, NPTS, DIM, DIM, bg, vt_h, NPTS, nullptr, 0, 0.f, nullptr);
  // S = q k^T - SHIFT (f16) + fused column exp-sums (atomics into colsum)
  gemm_bt<4, 0><<<dim3(NPTS / 128, NPTS / 128), blk, 0, stream>>>(
      q_h, DIM, k_h, DIM, NPTS, NPTS, DIM, nullptr, S, NPTS, nullptr, 0, SHIFT, colsum);
  inv_f32<<<NPTS / 256, 256, 0, stream>>>(colsum, NPTS);
  // out = P @ v + p ; P built on the fly in A-staging (exp * inv_cs)
  gemm_bt<3, 1><<<512, blk, 0, stream>>>(
      S, NPTS, vt_h, NPTS, NPTS, DIM, NPTS, nullptr, out, DIM, p, DIM, 0.f, colsum);
}

// Round 3
// 584.772 us; speedup vs baseline: 1.2430x; 1.2093x over previous
//
#include <hip/hip_runtime.h>
#include <hip/hip_fp16.h>

typedef _Float16 f16;
typedef __attribute__((ext_vector_type(8))) _Float16 f16x8;
typedef __attribute__((ext_vector_type(4))) float f32x4;

#define NPTS 8192
#define DIM  1024
#define HL2E 0.721347520444482f   // log2(e)/2
#define S2SHIFT 50.0f             // store exp((s-50)/2) in f16

// async global->LDS, 16B per lane; lds base must be wave-uniform
__device__ __forceinline__ void glds16(const void* g, void* l) {
  __builtin_amdgcn_global_load_lds(
      (const __attribute__((address_space(1))) void*)g,
      (__attribute__((address_space(3))) void*)l, 16, 0, 0);
}

// ---------- fp32 -> fp16 convert (vectorized, n multiple of 2048) ----------
__global__ void cvt_f32_f16(const float* __restrict__ src, f16* __restrict__ dst, int n) {
  int i = (blockIdx.x * 256 + threadIdx.x) * 8;
  if (i >= n) return;
  const float4* s = (const float4*)(src + i);
  float4 a = s[0], b = s[1];
  f16x8 o;
  o[0] = (f16)a.x; o[1] = (f16)a.y; o[2] = (f16)a.z; o[3] = (f16)a.w;
  o[4] = (f16)b.x; o[5] = (f16)b.y; o[6] = (f16)b.z; o[7] = (f16)b.w;
  *(f16x8*)(dst + i) = o;
}

__global__ void zero_f32(float* __restrict__ p, int n) {
  int i = blockIdx.x * 256 + threadIdx.x;
  if (i < n) p[i] = 0.f;
}

// colsum -> per-column scale factors: ics2 = cs^-1/2 (for v), ics4 = cs^-1/4 (for P staging)
__global__ void mk_scales(const float* __restrict__ colsum,
                          f16* __restrict__ ics2, f16* __restrict__ ics4) {
  int j = blockIdx.x * 256 + threadIdx.x;
  float r2 = rsqrtf(colsum[j]);
  ics2[j] = (f16)r2;
  ics4[j] = (f16)sqrtf(r2);
}

// vt[n][j] *= ics2[j]  (in place, 8-wide packed)
__global__ void vscale(f16* __restrict__ vt, const f16* __restrict__ ics2) {
  long i = ((long)blockIdx.x * 256 + threadIdx.x) * 8;
  f16x8 v = *(f16x8*)(vt + i);
  f16x8 s = *(const f16x8*)(ics2 + (i & (NPTS - 1)));
  *(f16x8*)(vt + i) = v * s;
}

// ---------- C = A * B^T f16 MFMA GEMM, 128x128 tile, BK=32, glds staging ----------
// EPI 0: f16 C[i,n] = acc + bias[n]                       (q,k projections)
// EPI 1: f16 C[n*ldc + i] = acc + bias[n]                 (transposed, v^T)
// EPI 4: QK^T — f16 C[i,n] = clamp(exp((acc-50)/2)); atomicAdd column sum of
//        (rounded value)^2 into colsum
// EPI 3: PV — A-staging (VGPR path): t = a*ics4[k]; stage t*t. B via glds.
//        f32 C[i,n] = acc + Res[i*ldr + n]
// SWZ 1: 1D grid, row = b&63, col = b>>6 (M=8192, N=1024): all 8 col-tiles of a
//        row-block land on one XCD -> A row-panel L2-hit 7/8 times.
template<int EPI, int SWZ>
__global__ __launch_bounds__(256, 2)
void gemm_bt(const f16* __restrict__ A, int lda,
             const f16* __restrict__ B, int ldb,
             int M, int N, int K,
             const float* __restrict__ bias,
             void* __restrict__ Cout, int ldc,
             const float* __restrict__ Res, int ldr,
             float* __restrict__ colsum, const f16* __restrict__ ics4) {
  __shared__ f16 sA[128 * 32];
  __shared__ f16 sB[128 * 32];
  const int t = threadIdx.x;
  const int w = t >> 6, l = t & 63;
  const int wm = (w >> 1) * 64, wn = (w & 1) * 64;   // 2x2 waves, 64x64 each
  long bi, bj;
  if (SWZ) {
    bi = (long)(blockIdx.x & 63) * 128;
    bj = (long)(blockIdx.x >> 6) * 128;
  } else {
    bi = (long)blockIdx.y * 128;
    bj = (long)blockIdx.x * 128;
  }
  const int lr = l & 15, lk = (l >> 4) * 8;

  // glds mapping: wave w stages rows [w*16, w*16+16) and +64; lane l -> row l>>2, chunk l&3
  const int grow = w * 16 + (l >> 2);
  const int gcol = (l & 3) * 8;
  const f16* gA = A + (bi + grow) * (long)lda + gcol;
  const f16* gB = B + (bj + grow) * (long)ldb + gcol;
  f16* lA0 = sA + (w * 16) * 32;         // wave-uniform LDS bases
  f16* lA1 = sA + (64 + w * 16) * 32;
  f16* lB0 = sB + (w * 16) * 32;
  f16* lB1 = sB + (64 + w * 16) * 32;

  // EPI3 A-side VGPR staging: thread -> row t>>2, chunk t&3
  const int sr = t >> 2, sc = (t & 3) * 8;
  const f16* gAs = A + (bi + sr) * (long)lda + sc;
  f16x8 ra0 = {}, ra1 = {}, icv = {};
  if (EPI == 3) {
    ra0 = *(const f16x8*)gAs;
    ra1 = *(const f16x8*)(gAs + 64l * lda);
    icv = *(const f16x8*)(ics4 + sc);
  }

  f32x4 acc[4][4] = {};

  for (int k0 = 0; k0 < K; k0 += 32) {
    __syncthreads();                        // prior frag reads done
    if (EPI == 3) {
      f16x8 t0 = ra0 * icv; t0 = t0 * t0;   // P = (e * cs^-1/4)^2 = e^2 / sqrt(cs)
      f16x8 t1 = ra1 * icv; t1 = t1 * t1;
      *(f16x8*)(sA + sr * 32 + sc) = t0;
      *(f16x8*)(sA + (sr + 64) * 32 + sc) = t1;
    } else {
      glds16(gA, lA0);
      glds16(gA + 64l * lda, lA1);
      gA += 32;
    }
    glds16(gB, lB0);
    glds16(gB + 64l * ldb, lB1);
    gB += 32;
    __syncthreads();                        // drains vmcnt(0)+lgkmcnt(0): tile ready
    if (EPI == 3 && k0 + 32 < K) {          // prefetch next A chunk over the MFMAs
      gAs += 32;
      ra0 = *(const f16x8*)gAs;
      ra1 = *(const f16x8*)(gAs + 64l * lda);
      icv = *(const f16x8*)(ics4 + k0 + 32 + sc);
    }
    f16x8 af[4], bf[4];
#pragma unroll
    for (int mt = 0; mt < 4; mt++)
      af[mt] = *(const f16x8*)(sA + (wm + mt * 16 + lr) * 32 + lk);
#pragma unroll
    for (int nt = 0; nt < 4; nt++)
      bf[nt] = *(const f16x8*)(sB + (wn + nt * 16 + lr) * 32 + lk);
#pragma unroll
    for (int mt = 0; mt < 4; mt++)
#pragma unroll
      for (int nt = 0; nt < 4; nt++)
        acc[mt][nt] = __builtin_amdgcn_mfma_f32_16x16x32_f16(af[mt], bf[nt], acc[mt][nt], 0, 0, 0);
  }

  // C/D layout (m89-verified): col = l&15, row = (l>>4)*4 + reg
  const int rbase = (l >> 4) * 4;
#pragma unroll
  for (int nt = 0; nt < 4; nt++) {
    const long col = bj + wn + nt * 16 + lr;
    float csum = 0.f;
#pragma unroll
    for (int mt = 0; mt < 4; mt++) {
      const long row0 = bi + wm + mt * 16 + rbase;
      if (EPI == 0) {
        float bb = bias[col];
        f16* C = (f16*)Cout;
#pragma unroll
        for (int g = 0; g < 4; g++)
          C[(row0 + g) * ldc + col] = (f16)(acc[mt][nt][g] + bb);
      } else if (EPI == 1) {
        float bb = bias[col];
        union { unsigned long long u; f16 h[4]; } pk;
#pragma unroll
        for (int g = 0; g < 4; g++) pk.h[g] = (f16)(acc[mt][nt][g] + bb);
        *(unsigned long long*)((f16*)Cout + col * (long)ldc + row0) = pk.u;  // 8B store
      } else if (EPI == 3) {
        float* C = (float*)Cout;
#pragma unroll
        for (int g = 0; g < 4; g++)
          C[(row0 + g) * ldc + col] = acc[mt][nt][g] + Res[(row0 + g) * (long)ldr + col];
      } else { // EPI 4: half-exp f16 store + column sum of squares of the ROUNDED value
        f16* C = (f16*)Cout;
#pragma unroll
        for (int g = 0; g < 4; g++) {
          float e = exp2f((acc[mt][nt][g] - S2SHIFT) * HL2E);
          e = fminf(e, 240.f);              // e^2 <= 57600 < f16 max; consistent num/denom
          f16 eh = (f16)e;
          C[(row0 + g) * ldc + col] = eh;
          float ef = (float)eh;
          csum += ef * ef;
        }
      }
    }
    if (EPI == 4) {
      csum += __shfl_xor(csum, 16);
      csum += __shfl_xor(csum, 32);
      if (l < 16) atomicAdd(colsum + col, csum);
    }
  }
}

extern "C" void kernel_launch(void* const* d_in, const int* in_sizes, int n_in,
                              void* d_out, int out_size, void* d_ws, size_t ws_size,
                              hipStream_t stream) {
  const float* p  = (const float*)d_in[0];
  const float* r  = (const float*)d_in[1];
  const float* Wh = (const float*)d_in[2];
  const float* bh = (const float*)d_in[3];
  const float* Wl = (const float*)d_in[4];
  const float* bl = (const float*)d_in[5];
  const float* Wg = (const float*)d_in[6];
  const float* bg = (const float*)d_in[7];
  float* out = (float*)d_out;

  char* ws = (char*)d_ws;
  f16* q_h  = (f16*)(ws + (0ull  << 20));   // 16 MB [N,D]
  f16* k_h  = (f16*)(ws + (16ull << 20));   // 16 MB [N,D]
  f16* vt_h = (f16*)(ws + (32ull << 20));   // 16 MB [D,N] (v^T; scaled in place)
  f16* p_h  = (f16*)(ws + (48ull << 20));   // 16 MB
  f16* r_h  = (f16*)(ws + (64ull << 20));   // 16 MB
  f16* wh_h = (f16*)(ws + (80ull << 20));   // 2 MB
  f16* wl_h = (f16*)(ws + (82ull << 20));
  f16* wg_h = (f16*)(ws + (84ull << 20));
  f16* S    = (f16*)(ws + (96ull << 20));   // 128 MB [N,N]: exp((s-50)/2) in f16
  float* colsum = (float*)(ws + (224ull << 20));  // 32 KB
  f16* ics2 = (f16*)(ws + (225ull << 20));        // 16 KB cs^-1/2
  f16* ics4 = (f16*)(ws + (226ull << 20));        // 16 KB cs^-1/4

  const int nP = NPTS * DIM, nW = DIM * DIM;
  cvt_f32_f16<<<nP / 2048, 256, 0, stream>>>(p,  p_h,  nP);
  cvt_f32_f16<<<nP / 2048, 256, 0, stream>>>(r,  r_h,  nP);
  cvt_f32_f16<<<nW / 2048, 256, 0, stream>>>(Wh, wh_h, nW);
  cvt_f32_f16<<<nW / 2048, 256, 0, stream>>>(Wl, wl_h, nW);
  cvt_f32_f16<<<nW / 2048, 256, 0, stream>>>(Wg, wg_h, nW);
  zero_f32<<<NPTS / 256, 256, 0, stream>>>(colsum, NPTS);

  dim3 blk(256);
  gemm_bt<0, 1><<<512, blk, 0, stream>>>(
      p_h, DIM, wh_h, DIM, NPTS, DIM, DIM, bh, q_h, DIM, nullptr, 0, nullptr, nullptr);
  gemm_bt<0, 1><<<512, blk, 0, stream>>>(
      r_h, DIM, wl_h, DIM, NPTS, DIM, DIM, bl, k_h, DIM, nullptr, 0, nullptr, nullptr);
  gemm_bt<1, 1><<<512, blk, 0, stream>>>(
      p_h, DIM, wg_h, DIM, NPTS, DIM, DIM, bg, vt_h, NPTS, nullptr, 0, nullptr, nullptr);
  // S = exp((q k^T - 50)/2) in f16, fused column sum of squares
  gemm_bt<4, 0><<<dim3(NPTS / 128, NPTS / 128), blk, 0, stream>>>(
      q_h, DIM, k_h, DIM, NPTS, NPTS, DIM, nullptr, S, NPTS, nullptr, 0, colsum, nullptr);
  mk_scales<<<NPTS / 256, 256, 0, stream>>>(colsum, ics2, ics4);
  vscale<<<(NPTS / 8) * (DIM / 256), 256, 0, stream>>>(vt_h, ics2);
  // out = P @ v~ + p ; P staged as (S * ics4)^2, B = v~ (pre-scaled by cs^-1/2)
  gemm_bt<3, 1><<<512, blk, 0, stream>>>(
      S, NPTS, vt_h, NPTS, NPTS, DIM, NPTS, nullptr, out, DIM, p, DIM, colsum, ics4);
}

// Round 4
// 581.455 us; speedup vs baseline: 1.2501x; 1.0057x over previous
//
#include <hip/hip_runtime.h>
#include <hip/hip_fp16.h>

typedef _Float16 f16;
typedef __attribute__((ext_vector_type(8))) _Float16 f16x8;
typedef __attribute__((ext_vector_type(4))) float f32x4;

#define NPTS 8192
#define DIM  1024
#define HL2E 0.721347520444482f   // log2(e)/2
#define S2SHIFT 50.0f             // store exp((s-50)/2) in f16
#define TBUF (128 * 32)           // one LDS tile buffer (f16 elems)

// async global->LDS, 16B per lane; lds base must be wave-uniform
__device__ __forceinline__ void glds16(const void* g, void* l) {
  __builtin_amdgcn_global_load_lds(
      (const __attribute__((address_space(1))) void*)g,
      (__attribute__((address_space(3))) void*)l, 16, 0, 0);
}

// ---------- fp32 -> fp16 convert (vectorized, n multiple of 2048) ----------
__global__ void cvt_f32_f16(const float* __restrict__ src, f16* __restrict__ dst, int n) {
  int i = (blockIdx.x * 256 + threadIdx.x) * 8;
  if (i >= n) return;
  const float4* s = (const float4*)(src + i);
  float4 a = s[0], b = s[1];
  f16x8 o;
  o[0] = (f16)a.x; o[1] = (f16)a.y; o[2] = (f16)a.z; o[3] = (f16)a.w;
  o[4] = (f16)b.x; o[5] = (f16)b.y; o[6] = (f16)b.z; o[7] = (f16)b.w;
  *(f16x8*)(dst + i) = o;
}

__global__ void zero_f32(float* __restrict__ p, int n) {
  int i = blockIdx.x * 256 + threadIdx.x;
  if (i < n) p[i] = 0.f;
}

// colsum -> per-column scale factors: ics2 = cs^-1/2 (for v), ics4 = cs^-1/4 (for P staging)
__global__ void mk_scales(const float* __restrict__ colsum,
                          f16* __restrict__ ics2, f16* __restrict__ ics4) {
  int j = blockIdx.x * 256 + threadIdx.x;
  float r2 = rsqrtf(colsum[j]);
  ics2[j] = (f16)r2;
  ics4[j] = (f16)sqrtf(r2);
}

// vt[n][j] *= ics2[j]  (in place, 8-wide packed)
__global__ void vscale(f16* __restrict__ vt, const f16* __restrict__ ics2) {
  long i = ((long)blockIdx.x * 256 + threadIdx.x) * 8;
  f16x8 v = *(f16x8*)(vt + i);
  f16x8 s = *(const f16x8*)(ics2 + (i & (NPTS - 1)));
  *(f16x8*)(vt + i) = v * s;
}

// ---------- C = A * B^T f16 MFMA GEMM, 128x128 tile, BK=32 ----------
// Single-barrier double-buffered pipeline: glds for tile k+1 is issued right
// after the barrier that drains tile k, and drained only by the NEXT barrier —
// the 16-MFMA block sits between issue and drain (latency hidden even at
// 2 blocks/CU, where the old issue->drain-immediately structure stalled
// ~850 cyc per K-step).
// EPI 0: f16 C[i,n] = acc + bias[n]                       (q,k projections)
// EPI 1: f16 C[n*ldc + i] = acc + bias[n]                 (transposed, v^T)
// EPI 4: QK^T — f16 C[i,n] = clamp(exp((acc-50)/2)); atomicAdd column sum of
//        (rounded value)^2 into colsum
// EPI 3: PV — A staged via VGPRs (regs loaded 2 tiles ahead): t = a*ics4; stage t*t.
//        B via glds. f32 C[i,n] = acc + Res[i*ldr + n]
// SWZ 1: 1D grid, row = b&63, col = b>>6 (M=8192): all 8 col-tiles of a
//        row-block land on one XCD -> A row-panel L2-hit 7/8 times.
template<int EPI, int SWZ>
__global__ __launch_bounds__(256, 2)
void gemm_bt(const f16* __restrict__ A, int lda,
             const f16* __restrict__ B, int ldb,
             int M, int N, int K,
             const float* __restrict__ bias,
             void* __restrict__ Cout, int ldc,
             const float* __restrict__ Res, int ldr,
             float* __restrict__ colsum, const f16* __restrict__ ics4) {
  __shared__ f16 sA[2 * TBUF];
  __shared__ f16 sB[2 * TBUF];
  const int t = threadIdx.x;
  const int w = t >> 6, l = t & 63;
  const int wm = (w >> 1) * 64, wn = (w & 1) * 64;   // 2x2 waves, 64x64 each
  long bi, bj;
  if (SWZ) {
    bi = (long)(blockIdx.x & 63) * 128;
    bj = (long)(blockIdx.x >> 6) * 128;
  } else {
    bi = (long)blockIdx.y * 128;
    bj = (long)blockIdx.x * 128;
  }
  const int lr = l & 15, lk = (l >> 4) * 8;

  // glds mapping: wave w stages rows [w*16, w*16+16) and +64; lane l -> row l>>2, chunk l&3
  const int grow = w * 16 + (l >> 2);
  const int gcol = (l & 3) * 8;
  const f16* gA = A + (bi + grow) * (long)lda + gcol;
  const f16* gB = B + (bj + grow) * (long)ldb + gcol;
  const int lw0 = (w * 16) * 32;          // wave-uniform LDS offsets within a buffer
  const int lw1 = (64 + w * 16) * 32;

  // EPI3 A-side VGPR staging: thread -> row t>>2, chunk t&3
  const int sr = t >> 2, sc = (t & 3) * 8;
  const f16* gAs = A + (bi + sr) * (long)lda + sc;
  f16x8 ra0 = {}, ra1 = {}, icv = {};

  const int nk = K >> 5;

  // ---- prologue: stage tile 0 into buffer 0 ----
  if (EPI == 3) {
    ra0 = *(const f16x8*)gAs;
    ra1 = *(const f16x8*)(gAs + 64l * lda);
    icv = *(const f16x8*)(ics4 + sc);
    f16x8 t0 = ra0 * icv; t0 = t0 * t0;   // P = (e * cs^-1/4)^2 = e^2 / sqrt(cs)
    f16x8 t1 = ra1 * icv; t1 = t1 * t1;
    *(f16x8*)(sA + sr * 32 + sc) = t0;
    *(f16x8*)(sA + (sr + 64) * 32 + sc) = t1;
    if (nk > 1) {                          // regs for tile 1
      gAs += 32;
      ra0 = *(const f16x8*)gAs;
      ra1 = *(const f16x8*)(gAs + 64l * lda);
      icv = *(const f16x8*)(ics4 + 32 + sc);
    }
  } else {
    glds16(gA, sA + lw0);
    glds16(gA + 64l * lda, sA + lw1);
    gA += 32;
  }
  glds16(gB, sB + lw0);
  glds16(gB + 64l * ldb, sB + lw1);
  gB += 32;

  f32x4 acc[4][4] = {};

  for (int k = 0; k < nk; k++) {
    const int cur = (k & 1) * TBUF, nxt = TBUF - cur;
    __syncthreads();                       // drains tile-k staging; protects nxt buffer
    if (k + 1 < nk) {                      // stage tile k+1 into the other buffer
      if (EPI == 3) {
        f16x8 t0 = ra0 * icv; t0 = t0 * t0;
        f16x8 t1 = ra1 * icv; t1 = t1 * t1;
        *(f16x8*)(sA + nxt + sr * 32 + sc) = t0;
        *(f16x8*)(sA + nxt + (sr + 64) * 32 + sc) = t1;
        if (k + 2 < nk) {                  // regs for tile k+2 (latency over MFMAs)
          gAs += 32;
          ra0 = *(const f16x8*)gAs;
          ra1 = *(const f16x8*)(gAs + 64l * lda);
          icv = *(const f16x8*)(ics4 + (k + 2) * 32 + sc);
        }
      } else {
        glds16(gA, sA + nxt + lw0);
        glds16(gA + 64l * lda, sA + nxt + lw1);
        gA += 32;
      }
      glds16(gB, sB + nxt + lw0);
      glds16(gB + 64l * ldb, sB + nxt + lw1);
      gB += 32;
    }
    f16x8 af[4], bf[4];
#pragma unroll
    for (int mt = 0; mt < 4; mt++)
      af[mt] = *(const f16x8*)(sA + cur + (wm + mt * 16 + lr) * 32 + lk);
#pragma unroll
    for (int nt = 0; nt < 4; nt++)
      bf[nt] = *(const f16x8*)(sB + cur + (wn + nt * 16 + lr) * 32 + lk);
#pragma unroll
    for (int mt = 0; mt < 4; mt++)
#pragma unroll
      for (int nt = 0; nt < 4; nt++)
        acc[mt][nt] = __builtin_amdgcn_mfma_f32_16x16x32_f16(af[mt], bf[nt], acc[mt][nt], 0, 0, 0);
  }

  // C/D layout (m89-verified): col = l&15, row = (l>>4)*4 + reg
  const int rbase = (l >> 4) * 4;
#pragma unroll
  for (int nt = 0; nt < 4; nt++) {
    const long col = bj + wn + nt * 16 + lr;
    float csum = 0.f;
#pragma unroll
    for (int mt = 0; mt < 4; mt++) {
      const long row0 = bi + wm + mt * 16 + rbase;
      if (EPI == 0) {
        float bb = bias[col];
        f16* C = (f16*)Cout;
#pragma unroll
        for (int g = 0; g < 4; g++)
          C[(row0 + g) * ldc + col] = (f16)(acc[mt][nt][g] + bb);
      } else if (EPI == 1) {
        float bb = bias[col];
        union { unsigned long long u; f16 h[4]; } pk;
#pragma unroll
        for (int g = 0; g < 4; g++) pk.h[g] = (f16)(acc[mt][nt][g] + bb);
        *(unsigned long long*)((f16*)Cout + col * (long)ldc + row0) = pk.u;  // 8B store
      } else if (EPI == 3) {
        float* C = (float*)Cout;
#pragma unroll
        for (int g = 0; g < 4; g++)
          C[(row0 + g) * ldc + col] = acc[mt][nt][g] + Res[(row0 + g) * (long)ldr + col];
      } else { // EPI 4: half-exp f16 store + column sum of squares of the ROUNDED value
        f16* C = (f16*)Cout;
#pragma unroll
        for (int g = 0; g < 4; g++) {
          float e = exp2f((acc[mt][nt][g] - S2SHIFT) * HL2E);
          e = fminf(e, 240.f);              // e^2 <= 57600 < f16 max; consistent num/denom
          f16 eh = (f16)e;
          C[(row0 + g) * ldc + col] = eh;
          float ef = (float)eh;
          csum += ef * ef;
        }
      }
    }
    if (EPI == 4) {
      csum += __shfl_xor(csum, 16);
      csum += __shfl_xor(csum, 32);
      if (l < 16) atomicAdd(colsum + col, csum);
    }
  }
}

extern "C" void kernel_launch(void* const* d_in, const int* in_sizes, int n_in,
                              void* d_out, int out_size, void* d_ws, size_t ws_size,
                              hipStream_t stream) {
  const float* p  = (const float*)d_in[0];
  const float* r  = (const float*)d_in[1];
  const float* Wh = (const float*)d_in[2];
  const float* bh = (const float*)d_in[3];
  const float* Wl = (const float*)d_in[4];
  const float* bl = (const float*)d_in[5];
  const float* Wg = (const float*)d_in[6];
  const float* bg = (const float*)d_in[7];
  float* out = (float*)d_out;

  char* ws = (char*)d_ws;
  f16* q_h  = (f16*)(ws + (0ull  << 20));   // 16 MB [N,D]
  f16* k_h  = (f16*)(ws + (16ull << 20));   // 16 MB [N,D]
  f16* vt_h = (f16*)(ws + (32ull << 20));   // 16 MB [D,N] (v^T; scaled in place)
  f16* p_h  = (f16*)(ws + (48ull << 20));   // 16 MB
  f16* r_h  = (f16*)(ws + (64ull << 20));   // 16 MB
  f16* wh_h = (f16*)(ws + (80ull << 20));   // 2 MB
  f16* wl_h = (f16*)(ws + (82ull << 20));
  f16* wg_h = (f16*)(ws + (84ull << 20));
  f16* S    = (f16*)(ws + (96ull << 20));   // 128 MB [N,N]: exp((s-50)/2) in f16
  float* colsum = (float*)(ws + (224ull << 20));  // 32 KB
  f16* ics2 = (f16*)(ws + (225ull << 20));        // 16 KB cs^-1/2
  f16* ics4 = (f16*)(ws + (226ull << 20));        // 16 KB cs^-1/4

  const int nP = NPTS * DIM, nW = DIM * DIM;
  cvt_f32_f16<<<nP / 2048, 256, 0, stream>>>(p,  p_h,  nP);
  cvt_f32_f16<<<nP / 2048, 256, 0, stream>>>(r,  r_h,  nP);
  cvt_f32_f16<<<nW / 2048, 256, 0, stream>>>(Wh, wh_h, nW);
  cvt_f32_f16<<<nW / 2048, 256, 0, stream>>>(Wl, wl_h, nW);
  cvt_f32_f16<<<nW / 2048, 256, 0, stream>>>(Wg, wg_h, nW);
  zero_f32<<<NPTS / 256, 256, 0, stream>>>(colsum, NPTS);

  dim3 blk(256);
  gemm_bt<0, 1><<<512, blk, 0, stream>>>(
      p_h, DIM, wh_h, DIM, NPTS, DIM, DIM, bh, q_h, DIM, nullptr, 0, nullptr, nullptr);
  gemm_bt<0, 1><<<512, blk, 0, stream>>>(
      r_h, DIM, wl_h, DIM, NPTS, DIM, DIM, bl, k_h, DIM, nullptr, 0, nullptr, nullptr);
  gemm_bt<1, 1><<<512, blk, 0, stream>>>(
      p_h, DIM, wg_h, DIM, NPTS, DIM, DIM, bg, vt_h, NPTS, nullptr, 0, nullptr, nullptr);
  // S = exp((q k^T - 50)/2) in f16, fused column sum of squares
  gemm_bt<4, 0><<<dim3(NPTS / 128, NPTS / 128), blk, 0, stream>>>(
      q_h, DIM, k_h, DIM, NPTS, NPTS, DIM, nullptr, S, NPTS, nullptr, 0, colsum, nullptr);
  mk_scales<<<NPTS / 256, 256, 0, stream>>>(colsum, ics2, ics4);
  vscale<<<(NPTS / 8) * (DIM / 256), 256, 0, stream>>>(vt_h, ics2);
  // out = P @ v~ + p ; P staged as (S * ics4)^2, B = v~ (pre-scaled by cs^-1/2)
  gemm_bt<3, 1><<<512, blk, 0, stream>>>(
      S, NPTS, vt_h, NPTS, NPTS, DIM, NPTS, nullptr, out, DIM, p, DIM, colsum, ics4);
}